// Round 3
// baseline (222.016 us; speedup 1.0000x reference)
//
#include <hip/hip_runtime.h>
#include <math.h>

#define BATCH 256
#define FB    64
#define NCOL  147456   // 128*128*3*3
#define TPB   256
#define BT    32       // batch tile per block

typedef float vfloat4 __attribute__((ext_vector_type(4)));  // native vector: OK for nontemporal builtins

// One wave (64 lanes == FB) per batch row; writes probs TRANSPOSED: PT[f][b].
__global__ void softmax_t(const float* __restrict__ x, float* __restrict__ pt) {
    const int b = blockIdx.x;
    const int lane = threadIdx.x;   // lane == filter index f
    float v = x[b * FB + lane];
    float m = v;
#pragma unroll
    for (int o = 32; o > 0; o >>= 1) m = fmaxf(m, __shfl_xor(m, o));
    float e = __expf(v - m);
    float s = e;
#pragma unroll
    for (int o = 32; o > 0; o >>= 1) s += __shfl_xor(s, o);
    pt[lane * BATCH + b] = e / s;
}

// out[b][n] = sum_f PT[f][b] * W[f][n]
// Block: 256 threads x 1 float4 col = 1024 cols, 32-batch tile.
// Probs arrive via wave-uniform global loads -> scalar pipe (SGPRs), so the
// vector pipes see only: 1 weight float4 load + 128 FMAs per f-step.
__global__ __launch_bounds__(TPB, 2) void bank_gemm(
        const float* __restrict__ W, const float* __restrict__ PT,
        float* __restrict__ out) {
    const int tid = threadIdx.x;
    const int ncol4 = NCOL / 4;
    const vfloat4* __restrict__ Wv = (const vfloat4*)W;
    const int c4 = blockIdx.x * TPB + tid;       // this thread's float4 column
    const int bg = blockIdx.y;
    const float* __restrict__ P0 = PT + bg * BT; // uniform base for this block

    vfloat4 acc[BT];
#pragma unroll
    for (int b = 0; b < BT; ++b) acc[b] = (vfloat4)(0.f);

    vfloat4 w = Wv[c4];
    for (int f = 0; f < FB; ++f) {
        vfloat4 wn = w;
        if (f + 1 < FB) wn = Wv[(f + 1) * ncol4 + c4];   // one-ahead prefetch
        const float* __restrict__ pr = P0 + f * BATCH;   // wave-uniform address
#pragma unroll
        for (int b = 0; b < BT; ++b) {
            const float p = pr[b];                       // -> s_load (SGPR)
            acc[b] = w * p + acc[b];                     // 4x v_fma_f32, SGPR operand
        }
        w = wn;
    }

    // Streaming (nontemporal) float4 stores: don't let 151 MB of output evict
    // the 37.7 MB weight working set from L3.
    vfloat4* Ov = (vfloat4*)out;
    const long long obase = (long long)(bg * BT) * ncol4 + c4;
#pragma unroll
    for (int b = 0; b < BT; ++b) {
        __builtin_nontemporal_store(acc[b], &Ov[obase + (long long)b * ncol4]);
    }
}

extern "C" void kernel_launch(void* const* d_in, const int* in_sizes, int n_in,
                              void* d_out, int out_size, void* d_ws, size_t ws_size,
                              hipStream_t stream) {
    const float* bank   = (const float*)d_in[0];   // (256, 64)
    const float* weight = (const float*)d_in[1];   // (64, 128,128,3,3)
    float* out    = (float*)d_out;                 // (256, 147456)
    float* probsT = (float*)d_ws;                  // 64*256 fp32 = 64 KB scratch

    softmax_t<<<BATCH, FB, 0, stream>>>(bank, probsT);

    dim3 grid(NCOL / (TPB * 4), BATCH / BT);
    bank_gemm<<<grid, TPB, 0, stream>>>(weight, probsT, out);
}